// Round 10
// baseline (513.538 us; speedup 1.0000x reference)
//
#include <hip/hip_runtime.h>
#include <hip/hip_bf16.h>

// GraphConvNet: embed -> 2x[ MLP(2x 128x128, relu) -> sym-norm gather/scatter
// aggregation -> skip -> LayerNorm ] -> segment-mean pool -> decode.
// R2: bf16 MFMA matmuls (W split hi+lo bf16). R5: atomic-free graph prep.
// R6: occupancy fixes. R7: scalar edge-index loads. R8: bf16 residual stream.
// R9: embed+MLP fusion, u16 partials. R10: agg splits each node's edge list
// across 2 waves (doubles outstanding gathers; serial s_load->gather chain was
// the limit at 3.5 TB/s, L2-fill floor 206MB=8x25.6MB table); prep at NPART=4
// via packed dual-u16 LDS counters (halves hist2/fill2 edge re-reads).

#define N_NODES 100000
#define N_EDGES 1600000
#define N_GRAPH 100
#define NPG     1000
#define LATENT  128

#define NPART   4
#define PSIZE   (N_NODES / NPART)     // 25000 nodes per range
#define NSLICE  64
#define ESLICE  (N_EDGES / NSLICE)    // 25000 edges per slice

#define SCAN_CHUNK 2048
#define SCAN_NB    ((N_NODES + SCAN_CHUNK - 1) / SCAN_CHUNK)   // 49

#define PCHUNK  20                    // pool chunks per graph
#define PCNODES (NPG / PCHUNK)        // 50 nodes per chunk

typedef __attribute__((ext_vector_type(8))) short short8;
typedef __attribute__((ext_vector_type(4))) float f32x4;

__device__ __forceinline__ unsigned short f2bf(float f) {
    union { float f; unsigned int u; } v; v.f = f;
    unsigned int r = v.u + 0x7fff + ((v.u >> 16) & 1);   // RTNE
    return (unsigned short)(r >> 16);
}
__device__ __forceinline__ float bf2f(unsigned short u) {
    union { unsigned int u; float f; } v; v.u = ((unsigned int)u) << 16;
    return v.f;
}

// ---------- dual LDS histogram, packed u16 counters (NPART=4) ----------------
// counter for node i lives in half (i&1) of word i>>1; carry-safe: per-slice
// per-node count <= ESLICE=25000 < 65536.
__global__ __launch_bounds__(1024) void k_hist2(const int* __restrict__ senders,
                                                const int* __restrict__ receivers,
                                                unsigned short* __restrict__ ps16,
                                                unsigned short* __restrict__ pr16) {
    __shared__ unsigned int cs[PSIZE / 2];         // 50 KB
    __shared__ unsigned int cr[PSIZE / 2];         // 50 KB
    int rg = blockIdx.x & (NPART - 1), sl = blockIdx.x >> 2;
    int lo = rg * PSIZE;
    for (int i = threadIdx.x; i < PSIZE / 2; i += 1024) { cs[i] = 0; cr[i] = 0; }
    __syncthreads();
    int e0 = sl * ESLICE;
    for (int e = e0 + threadIdx.x; e < e0 + ESLICE; e += 1024) {
        int s = senders[e] - lo;
        if ((unsigned)s < PSIZE) atomicAdd(&cs[s >> 1], 1u << ((s & 1) * 16));
        int r = receivers[e] - lo;
        if ((unsigned)r < PSIZE) atomicAdd(&cr[r >> 1], 1u << ((r & 1) * 16));
    }
    __syncthreads();
    size_t base = (size_t)(rg * NSLICE + sl) * PSIZE;
    for (int i = threadIdx.x; i < PSIZE; i += 1024) {
        ps16[base + i] = (unsigned short)((cs[i >> 1] >> ((i & 1) * 16)) & 0xffff);
        pr16[base + i] = (unsigned short)((cr[i >> 1] >> ((i & 1) * 16)) & 0xffff);
    }
}

// ---------- per-node scan over slices (pr16 in place -> local offsets) -------
__global__ __launch_bounds__(256) void k_scan_slices(const unsigned short* __restrict__ ps16,
                                                     unsigned short* __restrict__ pr16,
                                                     int* __restrict__ deg_r,
                                                     float* __restrict__ inv_s,
                                                     float* __restrict__ inv_r) {
    int n = blockIdx.x * 256 + threadIdx.x;
    if (n >= N_NODES) return;
    int rg = n / PSIZE, i = n - rg * PSIZE;
    size_t base = (size_t)rg * NSLICE * PSIZE + i;
    int run = 0, ss = 0;
#pragma unroll 4
    for (int sl = 0; sl < NSLICE; sl++) {
        size_t idx = base + (size_t)sl * PSIZE;
        int v = pr16[idx];
        pr16[idx] = (unsigned short)run;   // exclusive prefix over slices (local)
        run += v;
        ss += ps16[idx];
    }
    deg_r[n] = run;
    inv_r[n] = rsqrtf((float)(run + 1));   // +1 self loop
    inv_s[n] = rsqrtf((float)(ss + 1));
}

// ---------- multi-block exclusive scan of deg_r -> row_start ----------
__global__ __launch_bounds__(256) void k_scan_block(const int* __restrict__ deg,
                                                    int* __restrict__ blocksums, int n) {
    int b = blockIdx.x, t = threadIdx.x;
    int base = b * SCAN_CHUNK + t * 8;
    int s = 0;
#pragma unroll
    for (int j = 0; j < 8; j++) { int i = base + j; if (i < n) s += deg[i]; }
    __shared__ int wsum[4];
#pragma unroll
    for (int off = 32; off > 0; off >>= 1) s += __shfl_down(s, off, 64);
    if ((t & 63) == 0) wsum[t >> 6] = s;
    __syncthreads();
    if (t == 0) blocksums[b] = wsum[0] + wsum[1] + wsum[2] + wsum[3];
}

__global__ __launch_bounds__(64) void k_scan_top(int* __restrict__ blocksums, int nb) {
    int t = threadIdx.x;
    int v = (t < nb) ? blocksums[t] : 0;
    int inc = v;
#pragma unroll
    for (int off = 1; off < 64; off <<= 1) {
        int u = __shfl_up(inc, off, 64);
        if (t >= off) inc += u;
    }
    if (t < nb) blocksums[t] = inc - v;
}

__global__ __launch_bounds__(256) void k_scan_apply(const int* __restrict__ deg,
                                                    const int* __restrict__ blockoffs,
                                                    int* __restrict__ row_start, int n) {
    int b = blockIdx.x, t = threadIdx.x;
    int base = b * SCAN_CHUNK + t * 8;
    int v[8]; int tsum = 0;
#pragma unroll
    for (int j = 0; j < 8; j++) { int i = base + j; v[j] = (i < n) ? deg[i] : 0; tsum += v[j]; }
    __shared__ int wtot[4];
    int inc = tsum;
#pragma unroll
    for (int off = 1; off < 64; off <<= 1) {
        int u = __shfl_up(inc, off, 64);
        if ((t & 63) >= off) inc += u;
    }
    if ((t & 63) == 63) wtot[t >> 6] = inc;
    __syncthreads();
    int wbase = 0;
    for (int w = 0; w < (t >> 6); w++) wbase += wtot[w];
    int running = blockoffs[b] + wbase + (inc - tsum);
#pragma unroll
    for (int j = 0; j < 8; j++) {
        int i = base + j;
        if (i < n) {
            row_start[i] = running;
            running += v[j];
            if (i == n - 1) row_start[n] = running;
        }
    }
}

// ---------- CSR fill: bs = row_start + slice-local offset ----------
__global__ __launch_bounds__(1024) void k_fill2(const int* __restrict__ senders,
                                                const int* __restrict__ receivers,
                                                const unsigned short* __restrict__ pr16,
                                                const int* __restrict__ row_start,
                                                int* __restrict__ edge_src) {
    __shared__ int bs[PSIZE];                      // 100 KB
    int rg = blockIdx.x & (NPART - 1), sl = blockIdx.x >> 2;
    int lo = rg * PSIZE;
    const unsigned short* base = pr16 + (size_t)(rg * NSLICE + sl) * PSIZE;
    for (int i = threadIdx.x; i < PSIZE; i += 1024)
        bs[i] = row_start[lo + i] + (int)base[i];
    __syncthreads();
    int e0 = sl * ESLICE;
    for (int e = e0 + threadIdx.x; e < e0 + ESLICE; e += 1024) {
        int r = receivers[e] - lo;
        if ((unsigned)r < PSIZE) {
            int pos = atomicAdd(&bs[r], 1);        // LDS atomic only
            edge_src[pos] = senders[e];
        }
    }
}

// ---------- weight prep: pack bf16 hi/lo fragments in MFMA B-operand order ----
__global__ void k_wprep(const float* __restrict__ embed_w, const float* __restrict__ mlp_w,
                        unsigned short* __restrict__ hi, unsigned short* __restrict__ lo) {
    int t = blockIdx.x * 256 + threadIdx.x;
    if (t >= 8192 + 4 * 16384) return;
    const float* src; int local;
    if (t < 8192) { src = embed_w; local = t; }
    else { int m = t - 8192; src = mlp_w + (size_t)(m >> 14) * 16384; local = m & 16383; }
    int j = local & 7, lane = (local >> 3) & 63, tn = (local >> 9) & 7, kc = local >> 12;
    int k = kc * 32 + ((lane >> 4) << 3) + j;
    int n = tn * 16 + (lane & 15);
    float wv = src[k * 128 + n];
    unsigned short h = f2bf(wv);
    float rem = wv - bf2f(h);
    hi[t] = h; lo[t] = f2bf(rem);
}

// ---------- fused embed + MLP step 0 ----------------------------------------
__global__ __launch_bounds__(256) void k_embed_mlp(
    const float* __restrict__ A,
    const unsigned short* __restrict__ wehi, const unsigned short* __restrict__ welo,
    const float* __restrict__ eb,
    const unsigned short* __restrict__ w0hi, const unsigned short* __restrict__ w0lo,
    const unsigned short* __restrict__ w1hi, const unsigned short* __restrict__ w1lo,
    const float* __restrict__ b0, const float* __restrict__ b1,
    const float* __restrict__ inv_s,
    unsigned short* __restrict__ h16, unsigned short* __restrict__ x16, int M)
{
    __shared__ __align__(16) unsigned short t0[4][32][136];   // per-wave
    int t = threadIdx.x, w = t >> 6, L = t & 63;
    int m0 = blockIdx.x * 128 + w * 32;
    int lr = L & 15, lk = (L >> 4) * 8, lq = (L >> 4) * 4;

    float ebv[8], b0v[8], b1v[8];
#pragma unroll
    for (int tn = 0; tn < 8; tn++) {
        ebv[tn] = eb[tn * 16 + lr];
        b0v[tn] = b0[tn * 16 + lr];
        b1v[tn] = b1[tn * 16 + lr];
    }

    // ---- embed: nodes (fp32, K=64) @ We ----
    f32x4 acc[2][8];
#pragma unroll
    for (int bd = 0; bd < 2; bd++)
#pragma unroll
        for (int tn = 0; tn < 8; tn++) acc[bd][tn] = (f32x4){0.f, 0.f, 0.f, 0.f};
#pragma unroll
    for (int kc = 0; kc < 2; kc++) {
        short8 a[2];
#pragma unroll
        for (int bd = 0; bd < 2; bd++) {
            int grow = m0 + bd * 16 + lr; if (grow >= M) grow = M - 1;
            const float* rp = A + (size_t)grow * 64 + kc * 32 + lk;
            float4 v0 = *(const float4*)rp;
            float4 v1 = *(const float4*)(rp + 4);
            short8 pk;
            pk[0] = (short)f2bf(v0.x); pk[1] = (short)f2bf(v0.y);
            pk[2] = (short)f2bf(v0.z); pk[3] = (short)f2bf(v0.w);
            pk[4] = (short)f2bf(v1.x); pk[5] = (short)f2bf(v1.y);
            pk[6] = (short)f2bf(v1.z); pk[7] = (short)f2bf(v1.w);
            a[bd] = pk;
        }
#pragma unroll
        for (int tn = 0; tn < 8; tn++) {
            size_t fo = (size_t)(((kc * 8 + tn) * 64 + L)) * 8;
            short8 bh = *(const short8*)(wehi + fo);
            short8 bl = *(const short8*)(welo + fo);
#pragma unroll
            for (int bd = 0; bd < 2; bd++) {
                acc[bd][tn] = __builtin_amdgcn_mfma_f32_16x16x32_bf16(a[bd], bh, acc[bd][tn], 0, 0, 0);
                acc[bd][tn] = __builtin_amdgcn_mfma_f32_16x16x32_bf16(a[bd], bl, acc[bd][tn], 0, 0, 0);
            }
        }
    }
#pragma unroll
    for (int bd = 0; bd < 2; bd++)
#pragma unroll
        for (int tn = 0; tn < 8; tn++)
#pragma unroll
            for (int r = 0; r < 4; r++)
                t0[w][bd * 16 + lq + r][tn * 16 + lr] = f2bf(acc[bd][tn][r] + ebv[tn]);
#pragma unroll
    for (int q = 0; q < 8; q++) {
        int s = q * 64 + L;
        int row = s >> 4, c0 = (s & 15) * 8;
        int grow = m0 + row;
        if (grow < M)
            *(short8*)(h16 + (size_t)grow * 128 + c0) = *(const short8*)&t0[w][row][c0];
    }

    // ---- layer 1: t0 @ W0 ----
#pragma unroll
    for (int bd = 0; bd < 2; bd++)
#pragma unroll
        for (int tn = 0; tn < 8; tn++) acc[bd][tn] = (f32x4){0.f, 0.f, 0.f, 0.f};
#pragma unroll
    for (int kc = 0; kc < 4; kc++) {
        short8 a[2];
#pragma unroll
        for (int bd = 0; bd < 2; bd++)
            a[bd] = *(const short8*)&t0[w][bd * 16 + lr][kc * 32 + lk];
#pragma unroll
        for (int tn = 0; tn < 8; tn++) {
            size_t fo = (size_t)(((kc * 8 + tn) * 64 + L)) * 8;
            short8 bh = *(const short8*)(w0hi + fo);
            short8 bl = *(const short8*)(w0lo + fo);
#pragma unroll
            for (int bd = 0; bd < 2; bd++) {
                acc[bd][tn] = __builtin_amdgcn_mfma_f32_16x16x32_bf16(a[bd], bh, acc[bd][tn], 0, 0, 0);
                acc[bd][tn] = __builtin_amdgcn_mfma_f32_16x16x32_bf16(a[bd], bl, acc[bd][tn], 0, 0, 0);
            }
        }
    }
#pragma unroll
    for (int bd = 0; bd < 2; bd++)
#pragma unroll
        for (int tn = 0; tn < 8; tn++)
#pragma unroll
            for (int r = 0; r < 4; r++)
                t0[w][bd * 16 + lq + r][tn * 16 + lr] = f2bf(fmaxf(acc[bd][tn][r] + b0v[tn], 0.f));

    // ---- layer 2: t0 @ W1 ----
#pragma unroll
    for (int bd = 0; bd < 2; bd++)
#pragma unroll
        for (int tn = 0; tn < 8; tn++) acc[bd][tn] = (f32x4){0.f, 0.f, 0.f, 0.f};
#pragma unroll
    for (int kc = 0; kc < 4; kc++) {
        short8 a[2];
#pragma unroll
        for (int bd = 0; bd < 2; bd++)
            a[bd] = *(const short8*)&t0[w][bd * 16 + lr][kc * 32 + lk];
#pragma unroll
        for (int tn = 0; tn < 8; tn++) {
            size_t fo = (size_t)(((kc * 8 + tn) * 64 + L)) * 8;
            short8 bh = *(const short8*)(w1hi + fo);
            short8 bl = *(const short8*)(w1lo + fo);
#pragma unroll
            for (int bd = 0; bd < 2; bd++) {
                acc[bd][tn] = __builtin_amdgcn_mfma_f32_16x16x32_bf16(a[bd], bh, acc[bd][tn], 0, 0, 0);
                acc[bd][tn] = __builtin_amdgcn_mfma_f32_16x16x32_bf16(a[bd], bl, acc[bd][tn], 0, 0, 0);
            }
        }
    }
    float invs[2][4];
#pragma unroll
    for (int bd = 0; bd < 2; bd++)
#pragma unroll
        for (int r = 0; r < 4; r++) {
            int grow = m0 + bd * 16 + lq + r; if (grow >= M) grow = M - 1;
            invs[bd][r] = inv_s[grow];
        }
#pragma unroll
    for (int bd = 0; bd < 2; bd++)
#pragma unroll
        for (int tn = 0; tn < 8; tn++)
#pragma unroll
            for (int r = 0; r < 4; r++)
                t0[w][bd * 16 + lq + r][tn * 16 + lr] =
                    f2bf(fmaxf(acc[bd][tn][r] + b1v[tn], 0.f) * invs[bd][r]);
#pragma unroll
    for (int q = 0; q < 8; q++) {
        int s = q * 64 + L;
        int row = s >> 4, c0 = (s & 15) * 8;
        int grow = m0 + row;
        if (grow < M)
            *(short8*)(x16 + (size_t)grow * 128 + c0) = *(const short8*)&t0[w][row][c0];
    }
}

// ---------- MLP step 1 (reads h16 bf16 global) -------------------------------
__global__ __launch_bounds__(256) void k_mlp(
    const unsigned short* __restrict__ A16, const unsigned short* __restrict__ w0hi,
    const unsigned short* __restrict__ w0lo, const unsigned short* __restrict__ w1hi,
    const unsigned short* __restrict__ w1lo, const float* __restrict__ b0,
    const float* __restrict__ b1, const float* __restrict__ inv_s,
    unsigned short* __restrict__ x16, int M)
{
    __shared__ __align__(16) unsigned short t1[4][32][136];   // per-wave, barrier-free
    int t = threadIdx.x, w = t >> 6, L = t & 63;
    int m0 = blockIdx.x * 128 + w * 32;
    int lr = L & 15, lk = (L >> 4) * 8, lq = (L >> 4) * 4;

    float b0v[8], b1v[8];
#pragma unroll
    for (int tn = 0; tn < 8; tn++) { b0v[tn] = b0[tn * 16 + lr]; b1v[tn] = b1[tn * 16 + lr]; }

    f32x4 acc[2][8];
#pragma unroll
    for (int bd = 0; bd < 2; bd++)
#pragma unroll
        for (int tn = 0; tn < 8; tn++) acc[bd][tn] = (f32x4){0.f, 0.f, 0.f, 0.f};

#pragma unroll
    for (int kc = 0; kc < 4; kc++) {
        short8 a[2];
#pragma unroll
        for (int bd = 0; bd < 2; bd++) {
            int grow = m0 + bd * 16 + lr; if (grow >= M) grow = M - 1;
            a[bd] = *(const short8*)(A16 + (size_t)grow * 128 + kc * 32 + lk);
        }
#pragma unroll
        for (int tn = 0; tn < 8; tn++) {
            size_t fo = (size_t)(((kc * 8 + tn) * 64 + L)) * 8;
            short8 bh = *(const short8*)(w0hi + fo);
            short8 bl = *(const short8*)(w0lo + fo);
#pragma unroll
            for (int bd = 0; bd < 2; bd++) {
                acc[bd][tn] = __builtin_amdgcn_mfma_f32_16x16x32_bf16(a[bd], bh, acc[bd][tn], 0, 0, 0);
                acc[bd][tn] = __builtin_amdgcn_mfma_f32_16x16x32_bf16(a[bd], bl, acc[bd][tn], 0, 0, 0);
            }
        }
    }
#pragma unroll
    for (int bd = 0; bd < 2; bd++)
#pragma unroll
        for (int tn = 0; tn < 8; tn++)
#pragma unroll
            for (int r = 0; r < 4; r++)
                t1[w][bd * 16 + lq + r][tn * 16 + lr] = f2bf(fmaxf(acc[bd][tn][r] + b0v[tn], 0.f));

    f32x4 acc2[2][8];
#pragma unroll
    for (int bd = 0; bd < 2; bd++)
#pragma unroll
        for (int tn = 0; tn < 8; tn++) acc2[bd][tn] = (f32x4){0.f, 0.f, 0.f, 0.f};
#pragma unroll
    for (int kc = 0; kc < 4; kc++) {
        short8 a[2];
#pragma unroll
        for (int bd = 0; bd < 2; bd++)
            a[bd] = *(const short8*)&t1[w][bd * 16 + lr][kc * 32 + lk];
#pragma unroll
        for (int tn = 0; tn < 8; tn++) {
            size_t fo = (size_t)(((kc * 8 + tn) * 64 + L)) * 8;
            short8 bh = *(const short8*)(w1hi + fo);
            short8 bl = *(const short8*)(w1lo + fo);
#pragma unroll
            for (int bd = 0; bd < 2; bd++) {
                acc2[bd][tn] = __builtin_amdgcn_mfma_f32_16x16x32_bf16(a[bd], bh, acc2[bd][tn], 0, 0, 0);
                acc2[bd][tn] = __builtin_amdgcn_mfma_f32_16x16x32_bf16(a[bd], bl, acc2[bd][tn], 0, 0, 0);
            }
        }
    }
    float invs[2][4];
#pragma unroll
    for (int bd = 0; bd < 2; bd++)
#pragma unroll
        for (int r = 0; r < 4; r++) {
            int grow = m0 + bd * 16 + lq + r; if (grow >= M) grow = M - 1;
            invs[bd][r] = inv_s[grow];
        }
#pragma unroll
    for (int bd = 0; bd < 2; bd++)
#pragma unroll
        for (int tn = 0; tn < 8; tn++)
#pragma unroll
            for (int r = 0; r < 4; r++)
                t1[w][bd * 16 + lq + r][tn * 16 + lr] =
                    f2bf(fmaxf(acc2[bd][tn][r] + b1v[tn], 0.f) * invs[bd][r]);
#pragma unroll
    for (int q = 0; q < 8; q++) {
        int s = q * 64 + L;
        int row = s >> 4, c0 = (s & 15) * 8;
        int grow = m0 + row;
        if (grow < M)
            *(short8*)(x16 + (size_t)grow * 128 + c0) = *(const short8*)&t1[w][row][c0];
    }
}

// ---------- aggregation: 2 waves per node, halved edge lists -----------------
// block = 256 thr = 4 waves = 2 nodes; partials combined via LDS; even wave
// stores. Doubles outstanding gathers per node (serial chain was the limit).
__global__ __launch_bounds__(256) void k_agg_ln(
    const unsigned short* __restrict__ x16, const int* __restrict__ row_start,
    const int* __restrict__ edge_src, const float* __restrict__ inv_r,
    const float* __restrict__ ln_scale, const float* __restrict__ ln_offset,
    unsigned short* __restrict__ h16)
{
    __shared__ float2 part[4][64];
    int w = threadIdx.x >> 6, L = threadIdx.x & 63;
    int node = __builtin_amdgcn_readfirstlane(blockIdx.x * 2 + (w >> 1));
    int half = w & 1;
    const unsigned int* x32 = (const unsigned int*)x16;
    const unsigned int* h32 = (const unsigned int*)h16;

    float2 acc;
    if (half == 0) {
        unsigned int su = x32[(size_t)node * 64 + L];      // self loop
        acc.x = __uint_as_float(su << 16);
        acc.y = __uint_as_float(su & 0xffff0000u);
    } else {
        acc.x = 0.f; acc.y = 0.f;
    }

    int beg = row_start[node], end = row_start[node + 1];
    int mid = beg + ((end - beg) >> 1);
    int jb = half ? mid : beg;
    int je = half ? end : mid;
    int j = jb;
    for (; j + 8 <= je; j += 8) {
        unsigned int u[8];
#pragma unroll
        for (int q = 0; q < 8; q++) u[q] = x32[(size_t)edge_src[j + q] * 64 + L];
#pragma unroll
        for (int q = 0; q < 8; q++) {
            acc.x += __uint_as_float(u[q] << 16);
            acc.y += __uint_as_float(u[q] & 0xffff0000u);
        }
    }
    for (; j < je; j++) {
        unsigned int u0 = x32[(size_t)edge_src[j] * 64 + L];
        acc.x += __uint_as_float(u0 << 16);
        acc.y += __uint_as_float(u0 & 0xffff0000u);
    }

    part[w][L] = acc;
    __syncthreads();
    float2 o = part[w ^ 1][L];
    acc.x += o.x; acc.y += o.y;

    float ir = inv_r[node];
    unsigned int hu = h32[(size_t)node * 64 + L];
    float y0 = acc.x * ir + __uint_as_float(hu << 16);
    float y1 = acc.y * ir + __uint_as_float(hu & 0xffff0000u);

    float s1 = y0 + y1, s2 = y0 * y0 + y1 * y1;
#pragma unroll
    for (int off = 32; off > 0; off >>= 1) {
        s1 += __shfl_xor(s1, off, 64);
        s2 += __shfl_xor(s2, off, 64);
    }
    float mu = s1 * (1.f / 128.f);
    float var = fmaxf(s2 * (1.f / 128.f) - mu * mu, 0.f);
    float rstd = rsqrtf(var + 1e-5f);
    float2 sc = *(const float2*)&ln_scale[L * 2];
    float2 of = *(const float2*)&ln_offset[L * 2];
    float ox = (y0 - mu) * rstd * sc.x + of.x;
    float oy = (y1 - mu) * rstd * sc.y + of.y;
    if (half == 0)
        ((unsigned int*)h16)[(size_t)node * 64 + L] =
            (unsigned int)f2bf(ox) | ((unsigned int)f2bf(oy) << 16);
}

// ---------- pool phase 1: per-(graph,chunk) partial sums (bf16 h) ----------
__global__ __launch_bounds__(256) void k_pool1(const unsigned short* __restrict__ h16,
                                               float* __restrict__ partial) {
    int b = blockIdx.x;                       // 0 .. N_GRAPH*PCHUNK-1
    int g = b / PCHUNK, c = b % PCHUNK;
    int t = threadIdx.x, col = t & 127, half = t >> 7;
    const unsigned short* hg = h16 + ((size_t)g * NPG + (size_t)c * PCNODES) * 128;
    float acc = 0.f;
    for (int i = half; i < PCNODES; i += 2) acc += bf2f(hg[(size_t)i * 128 + col]);
    __shared__ float red[256];
    red[t] = acc;
    __syncthreads();
    if (half == 0) partial[(size_t)b * 128 + col] = red[col] + red[col + 128];
}

// ---------- pool phase 2: combine partials + decode ----------
__global__ __launch_bounds__(128) void k_pool2(const float* __restrict__ partial,
                                               const float* __restrict__ dec_w,
                                               const float* __restrict__ dec_b,
                                               float* __restrict__ out) {
    int g = blockIdx.x, col = threadIdx.x;    // 128 threads
    const float* pg = partial + (size_t)g * PCHUNK * 128;
    float s = 0.f;
#pragma unroll
    for (int c = 0; c < PCHUNK; c++) s += pg[c * 128 + col];
    s = s * (1.f / (float)NPG) * dec_w[col];
    __shared__ float ws[2];
#pragma unroll
    for (int off = 32; off > 0; off >>= 1) s += __shfl_down(s, off, 64);
    if ((col & 63) == 0) ws[col >> 6] = s;
    __syncthreads();
    if (col == 0) out[g] = ws[0] + ws[1] + dec_b[0];
}

extern "C" void kernel_launch(void* const* d_in, const int* in_sizes, int n_in,
                              void* d_out, int out_size, void* d_ws, size_t ws_size,
                              hipStream_t stream) {
    (void)in_sizes; (void)n_in; (void)out_size; (void)ws_size;
    const float* nodes     = (const float*)d_in[0];
    const int*   senders   = (const int*)d_in[1];
    const int*   receivers = (const int*)d_in[2];
    const float* embed_w   = (const float*)d_in[4];
    const float* embed_b   = (const float*)d_in[5];
    const float* mlp_w     = (const float*)d_in[6];
    const float* mlp_b     = (const float*)d_in[7];
    const float* ln_scale  = (const float*)d_in[8];
    const float* ln_offset = (const float*)d_in[9];
    const float* dec_w     = (const float*)d_in[10];
    const float* dec_b     = (const float*)d_in[11];
    float* out = (float*)d_out;

    const int N = N_NODES;
    const int WF_TOTAL = 8192 + 4 * 16384;          // frag elements (shorts)
    const size_t PART_TOTAL = (size_t)NPART * NSLICE * PSIZE;  // 6.4M entries

    char* p = (char*)d_ws;
    auto alloc = [&](size_t bytes) -> void* {
        void* r = (void*)p;
        p += (bytes + 255) & ~(size_t)255;
        return r;
    };
    unsigned short* h16      = (unsigned short*)alloc((size_t)N * 128 * 2);
    unsigned short* x16      = (unsigned short*)alloc((size_t)N * 128 * 2);
    int*            edge_src = (int*)alloc((size_t)N_EDGES * 4);
    unsigned short* ps16     = (unsigned short*)alloc(PART_TOTAL * 2);
    unsigned short* pr16     = (unsigned short*)alloc(PART_TOTAL * 2);
    int*            deg_r    = (int*)alloc((size_t)N * 4);
    float*          inv_s    = (float*)alloc((size_t)N * 4);
    float*          inv_r    = (float*)alloc((size_t)N * 4);
    int*            row_start= (int*)alloc((size_t)(N + 1) * 4);
    int*            blocksums= (int*)alloc((size_t)SCAN_NB * 4);
    unsigned short* wfhi     = (unsigned short*)alloc((size_t)WF_TOTAL * 2);
    unsigned short* wflo     = (unsigned short*)alloc((size_t)WF_TOTAL * 2);
    float*          poolpart = (float*)alloc((size_t)N_GRAPH * PCHUNK * 128 * 4);

    k_wprep<<<(WF_TOTAL + 255) / 256, 256, 0, stream>>>(embed_w, mlp_w, wfhi, wflo);

    // graph prep — no global atomics
    k_hist2<<<NPART * NSLICE, 1024, 0, stream>>>(senders, receivers, ps16, pr16);
    k_scan_slices<<<(N + 255) / 256, 256, 0, stream>>>(ps16, pr16, deg_r, inv_s, inv_r);
    k_scan_block<<<SCAN_NB, 256, 0, stream>>>(deg_r, blocksums, N);
    k_scan_top<<<1, 64, 0, stream>>>(blocksums, SCAN_NB);
    k_scan_apply<<<SCAN_NB, 256, 0, stream>>>(deg_r, blocksums, row_start, N);
    k_fill2<<<NPART * NSLICE, 1024, 0, stream>>>(senders, receivers, pr16, row_start, edge_src);

    int mblocks = (N + 127) / 128;
    const unsigned short* wehi = wfhi, *welo = wflo;
    const unsigned short* w0hi[2] = { wfhi + 8192,             wfhi + 8192 + 2 * 16384 };
    const unsigned short* w0lo[2] = { wflo + 8192,             wflo + 8192 + 2 * 16384 };
    const unsigned short* w1hi[2] = { wfhi + 8192 + 16384,     wfhi + 8192 + 3 * 16384 };
    const unsigned short* w1lo[2] = { wflo + 8192 + 16384,     wflo + 8192 + 3 * 16384 };

    // step 0: fused embed + MLP
    k_embed_mlp<<<mblocks, 256, 0, stream>>>(nodes, wehi, welo, embed_b,
                                             w0hi[0], w0lo[0], w1hi[0], w1lo[0],
                                             mlp_b, mlp_b + 128, inv_s, h16, x16, N);
    k_agg_ln<<<N / 2, 256, 0, stream>>>(x16, row_start, edge_src, inv_r,
                                        ln_scale, ln_offset, h16);
    // step 1
    k_mlp<<<mblocks, 256, 0, stream>>>(h16, w0hi[1], w0lo[1], w1hi[1], w1lo[1],
                                       mlp_b + 256, mlp_b + 384, inv_s, x16, N);
    k_agg_ln<<<N / 2, 256, 0, stream>>>(x16, row_start, edge_src, inv_r,
                                        ln_scale + 128, ln_offset + 128, h16);

    k_pool1<<<N_GRAPH * PCHUNK, 256, 0, stream>>>(h16, poolpart);
    k_pool2<<<N_GRAPH, 128, 0, stream>>>(poolpart, dec_w, dec_b, out);
}

// Round 11
// 396.176 us; speedup vs baseline: 1.2962x; 1.2962x over previous
//
#include <hip/hip_runtime.h>
#include <hip/hip_bf16.h>

// GraphConvNet: embed -> 2x[ MLP(2x 128x128, relu) -> sym-norm gather/scatter
// aggregation -> skip -> LayerNorm ] -> segment-mean pool -> decode.
// R2: bf16 MFMA matmuls (W split hi+lo bf16). R5: atomic-free graph prep.
// R6: occupancy fixes. R7: scalar edge-index loads. R8: bf16 residual stream.
// R9: embed+MLP fusion, u16 partials. R10 FAILED: 2-wave agg split halved BW
// (barrier skew + degenerate 8-wide unroll at deg/2~8); prep NPART=4 was good
// (-32us). R11: agg reverted to R9 single-wave-per-node; NPART=4 prep kept.

#define N_NODES 100000
#define N_EDGES 1600000
#define N_GRAPH 100
#define NPG     1000
#define LATENT  128

#define NPART   4
#define PSIZE   (N_NODES / NPART)     // 25000 nodes per range
#define NSLICE  64
#define ESLICE  (N_EDGES / NSLICE)    // 25000 edges per slice

#define SCAN_CHUNK 2048
#define SCAN_NB    ((N_NODES + SCAN_CHUNK - 1) / SCAN_CHUNK)   // 49

#define PCHUNK  20                    // pool chunks per graph
#define PCNODES (NPG / PCHUNK)        // 50 nodes per chunk

typedef __attribute__((ext_vector_type(8))) short short8;
typedef __attribute__((ext_vector_type(4))) float f32x4;

__device__ __forceinline__ unsigned short f2bf(float f) {
    union { float f; unsigned int u; } v; v.f = f;
    unsigned int r = v.u + 0x7fff + ((v.u >> 16) & 1);   // RTNE
    return (unsigned short)(r >> 16);
}
__device__ __forceinline__ float bf2f(unsigned short u) {
    union { unsigned int u; float f; } v; v.u = ((unsigned int)u) << 16;
    return v.f;
}

// ---------- dual LDS histogram, packed u16 counters (NPART=4) ----------------
__global__ __launch_bounds__(1024) void k_hist2(const int* __restrict__ senders,
                                                const int* __restrict__ receivers,
                                                unsigned short* __restrict__ ps16,
                                                unsigned short* __restrict__ pr16) {
    __shared__ unsigned int cs[PSIZE / 2];         // 50 KB
    __shared__ unsigned int cr[PSIZE / 2];         // 50 KB
    int rg = blockIdx.x & (NPART - 1), sl = blockIdx.x >> 2;
    int lo = rg * PSIZE;
    for (int i = threadIdx.x; i < PSIZE / 2; i += 1024) { cs[i] = 0; cr[i] = 0; }
    __syncthreads();
    int e0 = sl * ESLICE;
    for (int e = e0 + threadIdx.x; e < e0 + ESLICE; e += 1024) {
        int s = senders[e] - lo;
        if ((unsigned)s < PSIZE) atomicAdd(&cs[s >> 1], 1u << ((s & 1) * 16));
        int r = receivers[e] - lo;
        if ((unsigned)r < PSIZE) atomicAdd(&cr[r >> 1], 1u << ((r & 1) * 16));
    }
    __syncthreads();
    size_t base = (size_t)(rg * NSLICE + sl) * PSIZE;
    for (int i = threadIdx.x; i < PSIZE; i += 1024) {
        ps16[base + i] = (unsigned short)((cs[i >> 1] >> ((i & 1) * 16)) & 0xffff);
        pr16[base + i] = (unsigned short)((cr[i >> 1] >> ((i & 1) * 16)) & 0xffff);
    }
}

// ---------- per-node scan over slices (pr16 in place -> local offsets) -------
__global__ __launch_bounds__(256) void k_scan_slices(const unsigned short* __restrict__ ps16,
                                                     unsigned short* __restrict__ pr16,
                                                     int* __restrict__ deg_r,
                                                     float* __restrict__ inv_s,
                                                     float* __restrict__ inv_r) {
    int n = blockIdx.x * 256 + threadIdx.x;
    if (n >= N_NODES) return;
    int rg = n / PSIZE, i = n - rg * PSIZE;
    size_t base = (size_t)rg * NSLICE * PSIZE + i;
    int run = 0, ss = 0;
#pragma unroll 4
    for (int sl = 0; sl < NSLICE; sl++) {
        size_t idx = base + (size_t)sl * PSIZE;
        int v = pr16[idx];
        pr16[idx] = (unsigned short)run;   // exclusive prefix over slices (local)
        run += v;
        ss += ps16[idx];
    }
    deg_r[n] = run;
    inv_r[n] = rsqrtf((float)(run + 1));   // +1 self loop
    inv_s[n] = rsqrtf((float)(ss + 1));
}

// ---------- multi-block exclusive scan of deg_r -> row_start ----------
__global__ __launch_bounds__(256) void k_scan_block(const int* __restrict__ deg,
                                                    int* __restrict__ blocksums, int n) {
    int b = blockIdx.x, t = threadIdx.x;
    int base = b * SCAN_CHUNK + t * 8;
    int s = 0;
#pragma unroll
    for (int j = 0; j < 8; j++) { int i = base + j; if (i < n) s += deg[i]; }
    __shared__ int wsum[4];
#pragma unroll
    for (int off = 32; off > 0; off >>= 1) s += __shfl_down(s, off, 64);
    if ((t & 63) == 0) wsum[t >> 6] = s;
    __syncthreads();
    if (t == 0) blocksums[b] = wsum[0] + wsum[1] + wsum[2] + wsum[3];
}

__global__ __launch_bounds__(64) void k_scan_top(int* __restrict__ blocksums, int nb) {
    int t = threadIdx.x;
    int v = (t < nb) ? blocksums[t] : 0;
    int inc = v;
#pragma unroll
    for (int off = 1; off < 64; off <<= 1) {
        int u = __shfl_up(inc, off, 64);
        if (t >= off) inc += u;
    }
    if (t < nb) blocksums[t] = inc - v;
}

__global__ __launch_bounds__(256) void k_scan_apply(const int* __restrict__ deg,
                                                    const int* __restrict__ blockoffs,
                                                    int* __restrict__ row_start, int n) {
    int b = blockIdx.x, t = threadIdx.x;
    int base = b * SCAN_CHUNK + t * 8;
    int v[8]; int tsum = 0;
#pragma unroll
    for (int j = 0; j < 8; j++) { int i = base + j; v[j] = (i < n) ? deg[i] : 0; tsum += v[j]; }
    __shared__ int wtot[4];
    int inc = tsum;
#pragma unroll
    for (int off = 1; off < 64; off <<= 1) {
        int u = __shfl_up(inc, off, 64);
        if ((t & 63) >= off) inc += u;
    }
    if ((t & 63) == 63) wtot[t >> 6] = inc;
    __syncthreads();
    int wbase = 0;
    for (int w = 0; w < (t >> 6); w++) wbase += wtot[w];
    int running = blockoffs[b] + wbase + (inc - tsum);
#pragma unroll
    for (int j = 0; j < 8; j++) {
        int i = base + j;
        if (i < n) {
            row_start[i] = running;
            running += v[j];
            if (i == n - 1) row_start[n] = running;
        }
    }
}

// ---------- CSR fill: bs = row_start + slice-local offset ----------
__global__ __launch_bounds__(1024) void k_fill2(const int* __restrict__ senders,
                                                const int* __restrict__ receivers,
                                                const unsigned short* __restrict__ pr16,
                                                const int* __restrict__ row_start,
                                                int* __restrict__ edge_src) {
    __shared__ int bs[PSIZE];                      // 100 KB
    int rg = blockIdx.x & (NPART - 1), sl = blockIdx.x >> 2;
    int lo = rg * PSIZE;
    const unsigned short* base = pr16 + (size_t)(rg * NSLICE + sl) * PSIZE;
    for (int i = threadIdx.x; i < PSIZE; i += 1024)
        bs[i] = row_start[lo + i] + (int)base[i];
    __syncthreads();
    int e0 = sl * ESLICE;
    for (int e = e0 + threadIdx.x; e < e0 + ESLICE; e += 1024) {
        int r = receivers[e] - lo;
        if ((unsigned)r < PSIZE) {
            int pos = atomicAdd(&bs[r], 1);        // LDS atomic only
            edge_src[pos] = senders[e];
        }
    }
}

// ---------- weight prep: pack bf16 hi/lo fragments in MFMA B-operand order ----
__global__ void k_wprep(const float* __restrict__ embed_w, const float* __restrict__ mlp_w,
                        unsigned short* __restrict__ hi, unsigned short* __restrict__ lo) {
    int t = blockIdx.x * 256 + threadIdx.x;
    if (t >= 8192 + 4 * 16384) return;
    const float* src; int local;
    if (t < 8192) { src = embed_w; local = t; }
    else { int m = t - 8192; src = mlp_w + (size_t)(m >> 14) * 16384; local = m & 16383; }
    int j = local & 7, lane = (local >> 3) & 63, tn = (local >> 9) & 7, kc = local >> 12;
    int k = kc * 32 + ((lane >> 4) << 3) + j;
    int n = tn * 16 + (lane & 15);
    float wv = src[k * 128 + n];
    unsigned short h = f2bf(wv);
    float rem = wv - bf2f(h);
    hi[t] = h; lo[t] = f2bf(rem);
}

// ---------- fused embed + MLP step 0 ----------------------------------------
__global__ __launch_bounds__(256) void k_embed_mlp(
    const float* __restrict__ A,
    const unsigned short* __restrict__ wehi, const unsigned short* __restrict__ welo,
    const float* __restrict__ eb,
    const unsigned short* __restrict__ w0hi, const unsigned short* __restrict__ w0lo,
    const unsigned short* __restrict__ w1hi, const unsigned short* __restrict__ w1lo,
    const float* __restrict__ b0, const float* __restrict__ b1,
    const float* __restrict__ inv_s,
    unsigned short* __restrict__ h16, unsigned short* __restrict__ x16, int M)
{
    __shared__ __align__(16) unsigned short t0[4][32][136];   // per-wave
    int t = threadIdx.x, w = t >> 6, L = t & 63;
    int m0 = blockIdx.x * 128 + w * 32;
    int lr = L & 15, lk = (L >> 4) * 8, lq = (L >> 4) * 4;

    float ebv[8], b0v[8], b1v[8];
#pragma unroll
    for (int tn = 0; tn < 8; tn++) {
        ebv[tn] = eb[tn * 16 + lr];
        b0v[tn] = b0[tn * 16 + lr];
        b1v[tn] = b1[tn * 16 + lr];
    }

    // ---- embed: nodes (fp32, K=64) @ We ----
    f32x4 acc[2][8];
#pragma unroll
    for (int bd = 0; bd < 2; bd++)
#pragma unroll
        for (int tn = 0; tn < 8; tn++) acc[bd][tn] = (f32x4){0.f, 0.f, 0.f, 0.f};
#pragma unroll
    for (int kc = 0; kc < 2; kc++) {
        short8 a[2];
#pragma unroll
        for (int bd = 0; bd < 2; bd++) {
            int grow = m0 + bd * 16 + lr; if (grow >= M) grow = M - 1;
            const float* rp = A + (size_t)grow * 64 + kc * 32 + lk;
            float4 v0 = *(const float4*)rp;
            float4 v1 = *(const float4*)(rp + 4);
            short8 pk;
            pk[0] = (short)f2bf(v0.x); pk[1] = (short)f2bf(v0.y);
            pk[2] = (short)f2bf(v0.z); pk[3] = (short)f2bf(v0.w);
            pk[4] = (short)f2bf(v1.x); pk[5] = (short)f2bf(v1.y);
            pk[6] = (short)f2bf(v1.z); pk[7] = (short)f2bf(v1.w);
            a[bd] = pk;
        }
#pragma unroll
        for (int tn = 0; tn < 8; tn++) {
            size_t fo = (size_t)(((kc * 8 + tn) * 64 + L)) * 8;
            short8 bh = *(const short8*)(wehi + fo);
            short8 bl = *(const short8*)(welo + fo);
#pragma unroll
            for (int bd = 0; bd < 2; bd++) {
                acc[bd][tn] = __builtin_amdgcn_mfma_f32_16x16x32_bf16(a[bd], bh, acc[bd][tn], 0, 0, 0);
                acc[bd][tn] = __builtin_amdgcn_mfma_f32_16x16x32_bf16(a[bd], bl, acc[bd][tn], 0, 0, 0);
            }
        }
    }
#pragma unroll
    for (int bd = 0; bd < 2; bd++)
#pragma unroll
        for (int tn = 0; tn < 8; tn++)
#pragma unroll
            for (int r = 0; r < 4; r++)
                t0[w][bd * 16 + lq + r][tn * 16 + lr] = f2bf(acc[bd][tn][r] + ebv[tn]);
#pragma unroll
    for (int q = 0; q < 8; q++) {
        int s = q * 64 + L;
        int row = s >> 4, c0 = (s & 15) * 8;
        int grow = m0 + row;
        if (grow < M)
            *(short8*)(h16 + (size_t)grow * 128 + c0) = *(const short8*)&t0[w][row][c0];
    }

    // ---- layer 1: t0 @ W0 ----
#pragma unroll
    for (int bd = 0; bd < 2; bd++)
#pragma unroll
        for (int tn = 0; tn < 8; tn++) acc[bd][tn] = (f32x4){0.f, 0.f, 0.f, 0.f};
#pragma unroll
    for (int kc = 0; kc < 4; kc++) {
        short8 a[2];
#pragma unroll
        for (int bd = 0; bd < 2; bd++)
            a[bd] = *(const short8*)&t0[w][bd * 16 + lr][kc * 32 + lk];
#pragma unroll
        for (int tn = 0; tn < 8; tn++) {
            size_t fo = (size_t)(((kc * 8 + tn) * 64 + L)) * 8;
            short8 bh = *(const short8*)(w0hi + fo);
            short8 bl = *(const short8*)(w0lo + fo);
#pragma unroll
            for (int bd = 0; bd < 2; bd++) {
                acc[bd][tn] = __builtin_amdgcn_mfma_f32_16x16x32_bf16(a[bd], bh, acc[bd][tn], 0, 0, 0);
                acc[bd][tn] = __builtin_amdgcn_mfma_f32_16x16x32_bf16(a[bd], bl, acc[bd][tn], 0, 0, 0);
            }
        }
    }
#pragma unroll
    for (int bd = 0; bd < 2; bd++)
#pragma unroll
        for (int tn = 0; tn < 8; tn++)
#pragma unroll
            for (int r = 0; r < 4; r++)
                t0[w][bd * 16 + lq + r][tn * 16 + lr] = f2bf(fmaxf(acc[bd][tn][r] + b0v[tn], 0.f));

    // ---- layer 2: t0 @ W1 ----
#pragma unroll
    for (int bd = 0; bd < 2; bd++)
#pragma unroll
        for (int tn = 0; tn < 8; tn++) acc[bd][tn] = (f32x4){0.f, 0.f, 0.f, 0.f};
#pragma unroll
    for (int kc = 0; kc < 4; kc++) {
        short8 a[2];
#pragma unroll
        for (int bd = 0; bd < 2; bd++)
            a[bd] = *(const short8*)&t0[w][bd * 16 + lr][kc * 32 + lk];
#pragma unroll
        for (int tn = 0; tn < 8; tn++) {
            size_t fo = (size_t)(((kc * 8 + tn) * 64 + L)) * 8;
            short8 bh = *(const short8*)(w1hi + fo);
            short8 bl = *(const short8*)(w1lo + fo);
#pragma unroll
            for (int bd = 0; bd < 2; bd++) {
                acc[bd][tn] = __builtin_amdgcn_mfma_f32_16x16x32_bf16(a[bd], bh, acc[bd][tn], 0, 0, 0);
                acc[bd][tn] = __builtin_amdgcn_mfma_f32_16x16x32_bf16(a[bd], bl, acc[bd][tn], 0, 0, 0);
            }
        }
    }
    float invs[2][4];
#pragma unroll
    for (int bd = 0; bd < 2; bd++)
#pragma unroll
        for (int r = 0; r < 4; r++) {
            int grow = m0 + bd * 16 + lq + r; if (grow >= M) grow = M - 1;
            invs[bd][r] = inv_s[grow];
        }
#pragma unroll
    for (int bd = 0; bd < 2; bd++)
#pragma unroll
        for (int tn = 0; tn < 8; tn++)
#pragma unroll
            for (int r = 0; r < 4; r++)
                t0[w][bd * 16 + lq + r][tn * 16 + lr] =
                    f2bf(fmaxf(acc[bd][tn][r] + b1v[tn], 0.f) * invs[bd][r]);
#pragma unroll
    for (int q = 0; q < 8; q++) {
        int s = q * 64 + L;
        int row = s >> 4, c0 = (s & 15) * 8;
        int grow = m0 + row;
        if (grow < M)
            *(short8*)(x16 + (size_t)grow * 128 + c0) = *(const short8*)&t0[w][row][c0];
    }
}

// ---------- MLP step 1 (reads h16 bf16 global) -------------------------------
__global__ __launch_bounds__(256) void k_mlp(
    const unsigned short* __restrict__ A16, const unsigned short* __restrict__ w0hi,
    const unsigned short* __restrict__ w0lo, const unsigned short* __restrict__ w1hi,
    const unsigned short* __restrict__ w1lo, const float* __restrict__ b0,
    const float* __restrict__ b1, const float* __restrict__ inv_s,
    unsigned short* __restrict__ x16, int M)
{
    __shared__ __align__(16) unsigned short t1[4][32][136];   // per-wave, barrier-free
    int t = threadIdx.x, w = t >> 6, L = t & 63;
    int m0 = blockIdx.x * 128 + w * 32;
    int lr = L & 15, lk = (L >> 4) * 8, lq = (L >> 4) * 4;

    float b0v[8], b1v[8];
#pragma unroll
    for (int tn = 0; tn < 8; tn++) { b0v[tn] = b0[tn * 16 + lr]; b1v[tn] = b1[tn * 16 + lr]; }

    f32x4 acc[2][8];
#pragma unroll
    for (int bd = 0; bd < 2; bd++)
#pragma unroll
        for (int tn = 0; tn < 8; tn++) acc[bd][tn] = (f32x4){0.f, 0.f, 0.f, 0.f};

#pragma unroll
    for (int kc = 0; kc < 4; kc++) {
        short8 a[2];
#pragma unroll
        for (int bd = 0; bd < 2; bd++) {
            int grow = m0 + bd * 16 + lr; if (grow >= M) grow = M - 1;
            a[bd] = *(const short8*)(A16 + (size_t)grow * 128 + kc * 32 + lk);
        }
#pragma unroll
        for (int tn = 0; tn < 8; tn++) {
            size_t fo = (size_t)(((kc * 8 + tn) * 64 + L)) * 8;
            short8 bh = *(const short8*)(w0hi + fo);
            short8 bl = *(const short8*)(w0lo + fo);
#pragma unroll
            for (int bd = 0; bd < 2; bd++) {
                acc[bd][tn] = __builtin_amdgcn_mfma_f32_16x16x32_bf16(a[bd], bh, acc[bd][tn], 0, 0, 0);
                acc[bd][tn] = __builtin_amdgcn_mfma_f32_16x16x32_bf16(a[bd], bl, acc[bd][tn], 0, 0, 0);
            }
        }
    }
#pragma unroll
    for (int bd = 0; bd < 2; bd++)
#pragma unroll
        for (int tn = 0; tn < 8; tn++)
#pragma unroll
            for (int r = 0; r < 4; r++)
                t1[w][bd * 16 + lq + r][tn * 16 + lr] = f2bf(fmaxf(acc[bd][tn][r] + b0v[tn], 0.f));

    f32x4 acc2[2][8];
#pragma unroll
    for (int bd = 0; bd < 2; bd++)
#pragma unroll
        for (int tn = 0; tn < 8; tn++) acc2[bd][tn] = (f32x4){0.f, 0.f, 0.f, 0.f};
#pragma unroll
    for (int kc = 0; kc < 4; kc++) {
        short8 a[2];
#pragma unroll
        for (int bd = 0; bd < 2; bd++)
            a[bd] = *(const short8*)&t1[w][bd * 16 + lr][kc * 32 + lk];
#pragma unroll
        for (int tn = 0; tn < 8; tn++) {
            size_t fo = (size_t)(((kc * 8 + tn) * 64 + L)) * 8;
            short8 bh = *(const short8*)(w1hi + fo);
            short8 bl = *(const short8*)(w1lo + fo);
#pragma unroll
            for (int bd = 0; bd < 2; bd++) {
                acc2[bd][tn] = __builtin_amdgcn_mfma_f32_16x16x32_bf16(a[bd], bh, acc2[bd][tn], 0, 0, 0);
                acc2[bd][tn] = __builtin_amdgcn_mfma_f32_16x16x32_bf16(a[bd], bl, acc2[bd][tn], 0, 0, 0);
            }
        }
    }
    float invs[2][4];
#pragma unroll
    for (int bd = 0; bd < 2; bd++)
#pragma unroll
        for (int r = 0; r < 4; r++) {
            int grow = m0 + bd * 16 + lq + r; if (grow >= M) grow = M - 1;
            invs[bd][r] = inv_s[grow];
        }
#pragma unroll
    for (int bd = 0; bd < 2; bd++)
#pragma unroll
        for (int tn = 0; tn < 8; tn++)
#pragma unroll
            for (int r = 0; r < 4; r++)
                t1[w][bd * 16 + lq + r][tn * 16 + lr] =
                    f2bf(fmaxf(acc2[bd][tn][r] + b1v[tn], 0.f) * invs[bd][r]);
#pragma unroll
    for (int q = 0; q < 8; q++) {
        int s = q * 64 + L;
        int row = s >> 4, c0 = (s & 15) * 8;
        int grow = m0 + row;
        if (grow < M)
            *(short8*)(x16 + (size_t)grow * 128 + c0) = *(const short8*)&t1[w][row][c0];
    }
}

// ---------- aggregation (R9 form): 1 wave per node, scalar edge idx ----------
__global__ __launch_bounds__(256) void k_agg_ln(
    const unsigned short* __restrict__ x16, const int* __restrict__ row_start,
    const int* __restrict__ edge_src, const float* __restrict__ inv_r,
    const float* __restrict__ ln_scale, const float* __restrict__ ln_offset,
    unsigned short* __restrict__ h16)
{
    int node = __builtin_amdgcn_readfirstlane(blockIdx.x * 4 + (threadIdx.x >> 6));
    int L = threadIdx.x & 63;
    const unsigned int* x32 = (const unsigned int*)x16;
    const unsigned int* h32 = (const unsigned int*)h16;

    unsigned int su = x32[(size_t)node * 64 + L];          // self loop
    float2 acc;
    acc.x = __uint_as_float(su << 16);
    acc.y = __uint_as_float(su & 0xffff0000u);

    int beg = row_start[node], end = row_start[node + 1];
    int j = beg;
    for (; j + 8 <= end; j += 8) {
        unsigned int u[8];
#pragma unroll
        for (int q = 0; q < 8; q++) u[q] = x32[(size_t)edge_src[j + q] * 64 + L];
#pragma unroll
        for (int q = 0; q < 8; q++) {
            acc.x += __uint_as_float(u[q] << 16);
            acc.y += __uint_as_float(u[q] & 0xffff0000u);
        }
    }
    for (; j < end; j++) {
        unsigned int u0 = x32[(size_t)edge_src[j] * 64 + L];
        acc.x += __uint_as_float(u0 << 16);
        acc.y += __uint_as_float(u0 & 0xffff0000u);
    }

    float ir = inv_r[node];
    unsigned int hu = h32[(size_t)node * 64 + L];
    float y0 = acc.x * ir + __uint_as_float(hu << 16);
    float y1 = acc.y * ir + __uint_as_float(hu & 0xffff0000u);

    float s1 = y0 + y1, s2 = y0 * y0 + y1 * y1;
#pragma unroll
    for (int off = 32; off > 0; off >>= 1) {
        s1 += __shfl_xor(s1, off, 64);
        s2 += __shfl_xor(s2, off, 64);
    }
    float mu = s1 * (1.f / 128.f);
    float var = fmaxf(s2 * (1.f / 128.f) - mu * mu, 0.f);
    float rstd = rsqrtf(var + 1e-5f);
    float2 sc = *(const float2*)&ln_scale[L * 2];
    float2 of = *(const float2*)&ln_offset[L * 2];
    float ox = (y0 - mu) * rstd * sc.x + of.x;
    float oy = (y1 - mu) * rstd * sc.y + of.y;
    ((unsigned int*)h16)[(size_t)node * 64 + L] =
        (unsigned int)f2bf(ox) | ((unsigned int)f2bf(oy) << 16);
}

// ---------- pool phase 1: per-(graph,chunk) partial sums (bf16 h) ----------
__global__ __launch_bounds__(256) void k_pool1(const unsigned short* __restrict__ h16,
                                               float* __restrict__ partial) {
    int b = blockIdx.x;                       // 0 .. N_GRAPH*PCHUNK-1
    int g = b / PCHUNK, c = b % PCHUNK;
    int t = threadIdx.x, col = t & 127, half = t >> 7;
    const unsigned short* hg = h16 + ((size_t)g * NPG + (size_t)c * PCNODES) * 128;
    float acc = 0.f;
    for (int i = half; i < PCNODES; i += 2) acc += bf2f(hg[(size_t)i * 128 + col]);
    __shared__ float red[256];
    red[t] = acc;
    __syncthreads();
    if (half == 0) partial[(size_t)b * 128 + col] = red[col] + red[col + 128];
}

// ---------- pool phase 2: combine partials + decode ----------
__global__ __launch_bounds__(128) void k_pool2(const float* __restrict__ partial,
                                               const float* __restrict__ dec_w,
                                               const float* __restrict__ dec_b,
                                               float* __restrict__ out) {
    int g = blockIdx.x, col = threadIdx.x;    // 128 threads
    const float* pg = partial + (size_t)g * PCHUNK * 128;
    float s = 0.f;
#pragma unroll
    for (int c = 0; c < PCHUNK; c++) s += pg[c * 128 + col];
    s = s * (1.f / (float)NPG) * dec_w[col];
    __shared__ float ws[2];
#pragma unroll
    for (int off = 32; off > 0; off >>= 1) s += __shfl_down(s, off, 64);
    if ((col & 63) == 0) ws[col >> 6] = s;
    __syncthreads();
    if (col == 0) out[g] = ws[0] + ws[1] + dec_b[0];
}

extern "C" void kernel_launch(void* const* d_in, const int* in_sizes, int n_in,
                              void* d_out, int out_size, void* d_ws, size_t ws_size,
                              hipStream_t stream) {
    (void)in_sizes; (void)n_in; (void)out_size; (void)ws_size;
    const float* nodes     = (const float*)d_in[0];
    const int*   senders   = (const int*)d_in[1];
    const int*   receivers = (const int*)d_in[2];
    const float* embed_w   = (const float*)d_in[4];
    const float* embed_b   = (const float*)d_in[5];
    const float* mlp_w     = (const float*)d_in[6];
    const float* mlp_b     = (const float*)d_in[7];
    const float* ln_scale  = (const float*)d_in[8];
    const float* ln_offset = (const float*)d_in[9];
    const float* dec_w     = (const float*)d_in[10];
    const float* dec_b     = (const float*)d_in[11];
    float* out = (float*)d_out;

    const int N = N_NODES;
    const int WF_TOTAL = 8192 + 4 * 16384;          // frag elements (shorts)
    const size_t PART_TOTAL = (size_t)NPART * NSLICE * PSIZE;  // 6.4M entries

    char* p = (char*)d_ws;
    auto alloc = [&](size_t bytes) -> void* {
        void* r = (void*)p;
        p += (bytes + 255) & ~(size_t)255;
        return r;
    };
    unsigned short* h16      = (unsigned short*)alloc((size_t)N * 128 * 2);
    unsigned short* x16      = (unsigned short*)alloc((size_t)N * 128 * 2);
    int*            edge_src = (int*)alloc((size_t)N_EDGES * 4);
    unsigned short* ps16     = (unsigned short*)alloc(PART_TOTAL * 2);
    unsigned short* pr16     = (unsigned short*)alloc(PART_TOTAL * 2);
    int*            deg_r    = (int*)alloc((size_t)N * 4);
    float*          inv_s    = (float*)alloc((size_t)N * 4);
    float*          inv_r    = (float*)alloc((size_t)N * 4);
    int*            row_start= (int*)alloc((size_t)(N + 1) * 4);
    int*            blocksums= (int*)alloc((size_t)SCAN_NB * 4);
    unsigned short* wfhi     = (unsigned short*)alloc((size_t)WF_TOTAL * 2);
    unsigned short* wflo     = (unsigned short*)alloc((size_t)WF_TOTAL * 2);
    float*          poolpart = (float*)alloc((size_t)N_GRAPH * PCHUNK * 128 * 4);

    k_wprep<<<(WF_TOTAL + 255) / 256, 256, 0, stream>>>(embed_w, mlp_w, wfhi, wflo);

    // graph prep — no global atomics
    k_hist2<<<NPART * NSLICE, 1024, 0, stream>>>(senders, receivers, ps16, pr16);
    k_scan_slices<<<(N + 255) / 256, 256, 0, stream>>>(ps16, pr16, deg_r, inv_s, inv_r);
    k_scan_block<<<SCAN_NB, 256, 0, stream>>>(deg_r, blocksums, N);
    k_scan_top<<<1, 64, 0, stream>>>(blocksums, SCAN_NB);
    k_scan_apply<<<SCAN_NB, 256, 0, stream>>>(deg_r, blocksums, row_start, N);
    k_fill2<<<NPART * NSLICE, 1024, 0, stream>>>(senders, receivers, pr16, row_start, edge_src);

    int mblocks = (N + 127) / 128;
    const unsigned short* wehi = wfhi, *welo = wflo;
    const unsigned short* w0hi[2] = { wfhi + 8192,             wfhi + 8192 + 2 * 16384 };
    const unsigned short* w0lo[2] = { wflo + 8192,             wflo + 8192 + 2 * 16384 };
    const unsigned short* w1hi[2] = { wfhi + 8192 + 16384,     wfhi + 8192 + 3 * 16384 };
    const unsigned short* w1lo[2] = { wflo + 8192 + 16384,     wflo + 8192 + 3 * 16384 };

    // step 0: fused embed + MLP
    k_embed_mlp<<<mblocks, 256, 0, stream>>>(nodes, wehi, welo, embed_b,
                                             w0hi[0], w0lo[0], w1hi[0], w1lo[0],
                                             mlp_b, mlp_b + 128, inv_s, h16, x16, N);
    k_agg_ln<<<N / 4, 256, 0, stream>>>(x16, row_start, edge_src, inv_r,
                                        ln_scale, ln_offset, h16);
    // step 1
    k_mlp<<<mblocks, 256, 0, stream>>>(h16, w0hi[1], w0lo[1], w1hi[1], w1lo[1],
                                       mlp_b + 256, mlp_b + 384, inv_s, x16, N);
    k_agg_ln<<<N / 4, 256, 0, stream>>>(x16, row_start, edge_src, inv_r,
                                        ln_scale + 128, ln_offset + 128, h16);

    k_pool1<<<N_GRAPH * PCHUNK, 256, 0, stream>>>(h16, poolpart);
    k_pool2<<<N_GRAPH, 128, 0, stream>>>(poolpart, dec_w, dec_b, out);
}

// Round 12
// 392.691 us; speedup vs baseline: 1.3077x; 1.0089x over previous
//
#include <hip/hip_runtime.h>
#include <hip/hip_bf16.h>

// GraphConvNet: embed -> 2x[ MLP(2x 128x128, relu) -> sym-norm gather/scatter
// aggregation -> skip -> LayerNorm ] -> segment-mean pool -> decode.
// R2: bf16 MFMA matmuls (W split hi+lo bf16). R5: atomic-free graph prep.
// R6: occupancy fixes. R7: scalar edge-index loads. R8: bf16 residual stream.
// R9: embed+MLP fusion, u16 partials. R10: NPART=4 prep (kept), 2-wave agg
// (reverted: barrier skew + degenerate unroll). R12: pooling fused into agg
// step 1 (h16 write + pool1 h-read gone; one end-of-kernel barrier only),
// 16-deep gather batch (deg~16 -> 2x outstanding bytes for ~half the nodes),
// scan_top folded into scan_apply.

#define N_NODES 100000
#define N_EDGES 1600000
#define N_GRAPH 100
#define NPG     1000
#define LATENT  128

#define NPART   4
#define PSIZE   (N_NODES / NPART)     // 25000 nodes per range
#define NSLICE  64
#define ESLICE  (N_EDGES / NSLICE)    // 25000 edges per slice

#define SCAN_CHUNK 2048
#define SCAN_NB    ((N_NODES + SCAN_CHUNK - 1) / SCAN_CHUNK)   // 49

typedef __attribute__((ext_vector_type(8))) short short8;
typedef __attribute__((ext_vector_type(4))) float f32x4;

__device__ __forceinline__ unsigned short f2bf(float f) {
    union { float f; unsigned int u; } v; v.f = f;
    unsigned int r = v.u + 0x7fff + ((v.u >> 16) & 1);   // RTNE
    return (unsigned short)(r >> 16);
}
__device__ __forceinline__ float bf2f(unsigned short u) {
    union { unsigned int u; float f; } v; v.u = ((unsigned int)u) << 16;
    return v.f;
}

// ---------- dual LDS histogram, packed u16 counters (NPART=4) ----------------
__global__ __launch_bounds__(1024) void k_hist2(const int* __restrict__ senders,
                                                const int* __restrict__ receivers,
                                                unsigned short* __restrict__ ps16,
                                                unsigned short* __restrict__ pr16) {
    __shared__ unsigned int cs[PSIZE / 2];         // 50 KB
    __shared__ unsigned int cr[PSIZE / 2];         // 50 KB
    int rg = blockIdx.x & (NPART - 1), sl = blockIdx.x >> 2;
    int lo = rg * PSIZE;
    for (int i = threadIdx.x; i < PSIZE / 2; i += 1024) { cs[i] = 0; cr[i] = 0; }
    __syncthreads();
    int e0 = sl * ESLICE;
    for (int e = e0 + threadIdx.x; e < e0 + ESLICE; e += 1024) {
        int s = senders[e] - lo;
        if ((unsigned)s < PSIZE) atomicAdd(&cs[s >> 1], 1u << ((s & 1) * 16));
        int r = receivers[e] - lo;
        if ((unsigned)r < PSIZE) atomicAdd(&cr[r >> 1], 1u << ((r & 1) * 16));
    }
    __syncthreads();
    size_t base = (size_t)(rg * NSLICE + sl) * PSIZE;
    for (int i = threadIdx.x; i < PSIZE; i += 1024) {
        ps16[base + i] = (unsigned short)((cs[i >> 1] >> ((i & 1) * 16)) & 0xffff);
        pr16[base + i] = (unsigned short)((cr[i >> 1] >> ((i & 1) * 16)) & 0xffff);
    }
}

// ---------- per-node scan over slices (pr16 in place -> local offsets) -------
__global__ __launch_bounds__(256) void k_scan_slices(const unsigned short* __restrict__ ps16,
                                                     unsigned short* __restrict__ pr16,
                                                     int* __restrict__ deg_r,
                                                     float* __restrict__ inv_s,
                                                     float* __restrict__ inv_r) {
    int n = blockIdx.x * 256 + threadIdx.x;
    if (n >= N_NODES) return;
    int rg = n / PSIZE, i = n - rg * PSIZE;
    size_t base = (size_t)rg * NSLICE * PSIZE + i;
    int run = 0, ss = 0;
#pragma unroll 4
    for (int sl = 0; sl < NSLICE; sl++) {
        size_t idx = base + (size_t)sl * PSIZE;
        int v = pr16[idx];
        pr16[idx] = (unsigned short)run;   // exclusive prefix over slices (local)
        run += v;
        ss += ps16[idx];
    }
    deg_r[n] = run;
    inv_r[n] = rsqrtf((float)(run + 1));   // +1 self loop
    inv_s[n] = rsqrtf((float)(ss + 1));
}

// ---------- block sums of deg_r ----------
__global__ __launch_bounds__(256) void k_scan_block(const int* __restrict__ deg,
                                                    int* __restrict__ blocksums, int n) {
    int b = blockIdx.x, t = threadIdx.x;
    int base = b * SCAN_CHUNK + t * 8;
    int s = 0;
#pragma unroll
    for (int j = 0; j < 8; j++) { int i = base + j; if (i < n) s += deg[i]; }
    __shared__ int wsum[4];
#pragma unroll
    for (int off = 32; off > 0; off >>= 1) s += __shfl_down(s, off, 64);
    if ((t & 63) == 0) wsum[t >> 6] = s;
    __syncthreads();
    if (t == 0) blocksums[b] = wsum[0] + wsum[1] + wsum[2] + wsum[3];
}

// ---------- apply: block offset computed in-kernel from raw blocksums --------
__global__ __launch_bounds__(256) void k_scan_apply(const int* __restrict__ deg,
                                                    const int* __restrict__ blocksums,
                                                    int* __restrict__ row_start, int n) {
    __shared__ int boff_s;
    int b = blockIdx.x, t = threadIdx.x;
    // first wave: sum blocksums[0..b-1]  (SCAN_NB=49 <= 64)
    if (t < 64) {
        int v = (t < b && t < SCAN_NB) ? blocksums[t] : 0;
#pragma unroll
        for (int off = 32; off > 0; off >>= 1) v += __shfl_down(v, off, 64);
        if (t == 0) boff_s = v;
    }
    int base = b * SCAN_CHUNK + t * 8;
    int v[8]; int tsum = 0;
#pragma unroll
    for (int j = 0; j < 8; j++) { int i = base + j; v[j] = (i < n) ? deg[i] : 0; tsum += v[j]; }
    __shared__ int wtot[4];
    int inc = tsum;
#pragma unroll
    for (int off = 1; off < 64; off <<= 1) {
        int u = __shfl_up(inc, off, 64);
        if ((t & 63) >= off) inc += u;
    }
    if ((t & 63) == 63) wtot[t >> 6] = inc;
    __syncthreads();
    int wbase = 0;
    for (int w = 0; w < (t >> 6); w++) wbase += wtot[w];
    int running = boff_s + wbase + (inc - tsum);
#pragma unroll
    for (int j = 0; j < 8; j++) {
        int i = base + j;
        if (i < n) {
            row_start[i] = running;
            running += v[j];
            if (i == n - 1) row_start[n] = running;
        }
    }
}

// ---------- CSR fill: bs = row_start + slice-local offset ----------
__global__ __launch_bounds__(1024) void k_fill2(const int* __restrict__ senders,
                                                const int* __restrict__ receivers,
                                                const unsigned short* __restrict__ pr16,
                                                const int* __restrict__ row_start,
                                                int* __restrict__ edge_src) {
    __shared__ int bs[PSIZE];                      // 100 KB
    int rg = blockIdx.x & (NPART - 1), sl = blockIdx.x >> 2;
    int lo = rg * PSIZE;
    const unsigned short* base = pr16 + (size_t)(rg * NSLICE + sl) * PSIZE;
    for (int i = threadIdx.x; i < PSIZE; i += 1024)
        bs[i] = row_start[lo + i] + (int)base[i];
    __syncthreads();
    int e0 = sl * ESLICE;
    for (int e = e0 + threadIdx.x; e < e0 + ESLICE; e += 1024) {
        int r = receivers[e] - lo;
        if ((unsigned)r < PSIZE) {
            int pos = atomicAdd(&bs[r], 1);        // LDS atomic only
            edge_src[pos] = senders[e];
        }
    }
}

// ---------- weight prep: pack bf16 hi/lo fragments in MFMA B-operand order ----
__global__ void k_wprep(const float* __restrict__ embed_w, const float* __restrict__ mlp_w,
                        unsigned short* __restrict__ hi, unsigned short* __restrict__ lo) {
    int t = blockIdx.x * 256 + threadIdx.x;
    if (t >= 8192 + 4 * 16384) return;
    const float* src; int local;
    if (t < 8192) { src = embed_w; local = t; }
    else { int m = t - 8192; src = mlp_w + (size_t)(m >> 14) * 16384; local = m & 16383; }
    int j = local & 7, lane = (local >> 3) & 63, tn = (local >> 9) & 7, kc = local >> 12;
    int k = kc * 32 + ((lane >> 4) << 3) + j;
    int n = tn * 16 + (lane & 15);
    float wv = src[k * 128 + n];
    unsigned short h = f2bf(wv);
    float rem = wv - bf2f(h);
    hi[t] = h; lo[t] = f2bf(rem);
}

// ---------- fused embed + MLP step 0 ----------------------------------------
__global__ __launch_bounds__(256) void k_embed_mlp(
    const float* __restrict__ A,
    const unsigned short* __restrict__ wehi, const unsigned short* __restrict__ welo,
    const float* __restrict__ eb,
    const unsigned short* __restrict__ w0hi, const unsigned short* __restrict__ w0lo,
    const unsigned short* __restrict__ w1hi, const unsigned short* __restrict__ w1lo,
    const float* __restrict__ b0, const float* __restrict__ b1,
    const float* __restrict__ inv_s,
    unsigned short* __restrict__ h16, unsigned short* __restrict__ x16, int M)
{
    __shared__ __align__(16) unsigned short t0[4][32][136];   // per-wave
    int t = threadIdx.x, w = t >> 6, L = t & 63;
    int m0 = blockIdx.x * 128 + w * 32;
    int lr = L & 15, lk = (L >> 4) * 8, lq = (L >> 4) * 4;

    float ebv[8], b0v[8], b1v[8];
#pragma unroll
    for (int tn = 0; tn < 8; tn++) {
        ebv[tn] = eb[tn * 16 + lr];
        b0v[tn] = b0[tn * 16 + lr];
        b1v[tn] = b1[tn * 16 + lr];
    }

    // ---- embed: nodes (fp32, K=64) @ We ----
    f32x4 acc[2][8];
#pragma unroll
    for (int bd = 0; bd < 2; bd++)
#pragma unroll
        for (int tn = 0; tn < 8; tn++) acc[bd][tn] = (f32x4){0.f, 0.f, 0.f, 0.f};
#pragma unroll
    for (int kc = 0; kc < 2; kc++) {
        short8 a[2];
#pragma unroll
        for (int bd = 0; bd < 2; bd++) {
            int grow = m0 + bd * 16 + lr; if (grow >= M) grow = M - 1;
            const float* rp = A + (size_t)grow * 64 + kc * 32 + lk;
            float4 v0 = *(const float4*)rp;
            float4 v1 = *(const float4*)(rp + 4);
            short8 pk;
            pk[0] = (short)f2bf(v0.x); pk[1] = (short)f2bf(v0.y);
            pk[2] = (short)f2bf(v0.z); pk[3] = (short)f2bf(v0.w);
            pk[4] = (short)f2bf(v1.x); pk[5] = (short)f2bf(v1.y);
            pk[6] = (short)f2bf(v1.z); pk[7] = (short)f2bf(v1.w);
            a[bd] = pk;
        }
#pragma unroll
        for (int tn = 0; tn < 8; tn++) {
            size_t fo = (size_t)(((kc * 8 + tn) * 64 + L)) * 8;
            short8 bh = *(const short8*)(wehi + fo);
            short8 bl = *(const short8*)(welo + fo);
#pragma unroll
            for (int bd = 0; bd < 2; bd++) {
                acc[bd][tn] = __builtin_amdgcn_mfma_f32_16x16x32_bf16(a[bd], bh, acc[bd][tn], 0, 0, 0);
                acc[bd][tn] = __builtin_amdgcn_mfma_f32_16x16x32_bf16(a[bd], bl, acc[bd][tn], 0, 0, 0);
            }
        }
    }
#pragma unroll
    for (int bd = 0; bd < 2; bd++)
#pragma unroll
        for (int tn = 0; tn < 8; tn++)
#pragma unroll
            for (int r = 0; r < 4; r++)
                t0[w][bd * 16 + lq + r][tn * 16 + lr] = f2bf(acc[bd][tn][r] + ebv[tn]);
#pragma unroll
    for (int q = 0; q < 8; q++) {
        int s = q * 64 + L;
        int row = s >> 4, c0 = (s & 15) * 8;
        int grow = m0 + row;
        if (grow < M)
            *(short8*)(h16 + (size_t)grow * 128 + c0) = *(const short8*)&t0[w][row][c0];
    }

    // ---- layer 1: t0 @ W0 ----
#pragma unroll
    for (int bd = 0; bd < 2; bd++)
#pragma unroll
        for (int tn = 0; tn < 8; tn++) acc[bd][tn] = (f32x4){0.f, 0.f, 0.f, 0.f};
#pragma unroll
    for (int kc = 0; kc < 4; kc++) {
        short8 a[2];
#pragma unroll
        for (int bd = 0; bd < 2; bd++)
            a[bd] = *(const short8*)&t0[w][bd * 16 + lr][kc * 32 + lk];
#pragma unroll
        for (int tn = 0; tn < 8; tn++) {
            size_t fo = (size_t)(((kc * 8 + tn) * 64 + L)) * 8;
            short8 bh = *(const short8*)(w0hi + fo);
            short8 bl = *(const short8*)(w0lo + fo);
#pragma unroll
            for (int bd = 0; bd < 2; bd++) {
                acc[bd][tn] = __builtin_amdgcn_mfma_f32_16x16x32_bf16(a[bd], bh, acc[bd][tn], 0, 0, 0);
                acc[bd][tn] = __builtin_amdgcn_mfma_f32_16x16x32_bf16(a[bd], bl, acc[bd][tn], 0, 0, 0);
            }
        }
    }
#pragma unroll
    for (int bd = 0; bd < 2; bd++)
#pragma unroll
        for (int tn = 0; tn < 8; tn++)
#pragma unroll
            for (int r = 0; r < 4; r++)
                t0[w][bd * 16 + lq + r][tn * 16 + lr] = f2bf(fmaxf(acc[bd][tn][r] + b0v[tn], 0.f));

    // ---- layer 2: t0 @ W1 ----
#pragma unroll
    for (int bd = 0; bd < 2; bd++)
#pragma unroll
        for (int tn = 0; tn < 8; tn++) acc[bd][tn] = (f32x4){0.f, 0.f, 0.f, 0.f};
#pragma unroll
    for (int kc = 0; kc < 4; kc++) {
        short8 a[2];
#pragma unroll
        for (int bd = 0; bd < 2; bd++)
            a[bd] = *(const short8*)&t0[w][bd * 16 + lr][kc * 32 + lk];
#pragma unroll
        for (int tn = 0; tn < 8; tn++) {
            size_t fo = (size_t)(((kc * 8 + tn) * 64 + L)) * 8;
            short8 bh = *(const short8*)(w1hi + fo);
            short8 bl = *(const short8*)(w1lo + fo);
#pragma unroll
            for (int bd = 0; bd < 2; bd++) {
                acc[bd][tn] = __builtin_amdgcn_mfma_f32_16x16x32_bf16(a[bd], bh, acc[bd][tn], 0, 0, 0);
                acc[bd][tn] = __builtin_amdgcn_mfma_f32_16x16x32_bf16(a[bd], bl, acc[bd][tn], 0, 0, 0);
            }
        }
    }
    float invs[2][4];
#pragma unroll
    for (int bd = 0; bd < 2; bd++)
#pragma unroll
        for (int r = 0; r < 4; r++) {
            int grow = m0 + bd * 16 + lq + r; if (grow >= M) grow = M - 1;
            invs[bd][r] = inv_s[grow];
        }
#pragma unroll
    for (int bd = 0; bd < 2; bd++)
#pragma unroll
        for (int tn = 0; tn < 8; tn++)
#pragma unroll
            for (int r = 0; r < 4; r++)
                t0[w][bd * 16 + lq + r][tn * 16 + lr] =
                    f2bf(fmaxf(acc[bd][tn][r] + b1v[tn], 0.f) * invs[bd][r]);
#pragma unroll
    for (int q = 0; q < 8; q++) {
        int s = q * 64 + L;
        int row = s >> 4, c0 = (s & 15) * 8;
        int grow = m0 + row;
        if (grow < M)
            *(short8*)(x16 + (size_t)grow * 128 + c0) = *(const short8*)&t0[w][row][c0];
    }
}

// ---------- MLP step 1 (reads h16 bf16 global) -------------------------------
__global__ __launch_bounds__(256) void k_mlp(
    const unsigned short* __restrict__ A16, const unsigned short* __restrict__ w0hi,
    const unsigned short* __restrict__ w0lo, const unsigned short* __restrict__ w1hi,
    const unsigned short* __restrict__ w1lo, const float* __restrict__ b0,
    const float* __restrict__ b1, const float* __restrict__ inv_s,
    unsigned short* __restrict__ x16, int M)
{
    __shared__ __align__(16) unsigned short t1[4][32][136];   // per-wave, barrier-free
    int t = threadIdx.x, w = t >> 6, L = t & 63;
    int m0 = blockIdx.x * 128 + w * 32;
    int lr = L & 15, lk = (L >> 4) * 8, lq = (L >> 4) * 4;

    float b0v[8], b1v[8];
#pragma unroll
    for (int tn = 0; tn < 8; tn++) { b0v[tn] = b0[tn * 16 + lr]; b1v[tn] = b1[tn * 16 + lr]; }

    f32x4 acc[2][8];
#pragma unroll
    for (int bd = 0; bd < 2; bd++)
#pragma unroll
        for (int tn = 0; tn < 8; tn++) acc[bd][tn] = (f32x4){0.f, 0.f, 0.f, 0.f};

#pragma unroll
    for (int kc = 0; kc < 4; kc++) {
        short8 a[2];
#pragma unroll
        for (int bd = 0; bd < 2; bd++) {
            int grow = m0 + bd * 16 + lr; if (grow >= M) grow = M - 1;
            a[bd] = *(const short8*)(A16 + (size_t)grow * 128 + kc * 32 + lk);
        }
#pragma unroll
        for (int tn = 0; tn < 8; tn++) {
            size_t fo = (size_t)(((kc * 8 + tn) * 64 + L)) * 8;
            short8 bh = *(const short8*)(w0hi + fo);
            short8 bl = *(const short8*)(w0lo + fo);
#pragma unroll
            for (int bd = 0; bd < 2; bd++) {
                acc[bd][tn] = __builtin_amdgcn_mfma_f32_16x16x32_bf16(a[bd], bh, acc[bd][tn], 0, 0, 0);
                acc[bd][tn] = __builtin_amdgcn_mfma_f32_16x16x32_bf16(a[bd], bl, acc[bd][tn], 0, 0, 0);
            }
        }
    }
#pragma unroll
    for (int bd = 0; bd < 2; bd++)
#pragma unroll
        for (int tn = 0; tn < 8; tn++)
#pragma unroll
            for (int r = 0; r < 4; r++)
                t1[w][bd * 16 + lq + r][tn * 16 + lr] = f2bf(fmaxf(acc[bd][tn][r] + b0v[tn], 0.f));

    f32x4 acc2[2][8];
#pragma unroll
    for (int bd = 0; bd < 2; bd++)
#pragma unroll
        for (int tn = 0; tn < 8; tn++) acc2[bd][tn] = (f32x4){0.f, 0.f, 0.f, 0.f};
#pragma unroll
    for (int kc = 0; kc < 4; kc++) {
        short8 a[2];
#pragma unroll
        for (int bd = 0; bd < 2; bd++)
            a[bd] = *(const short8*)&t1[w][bd * 16 + lr][kc * 32 + lk];
#pragma unroll
        for (int tn = 0; tn < 8; tn++) {
            size_t fo = (size_t)(((kc * 8 + tn) * 64 + L)) * 8;
            short8 bh = *(const short8*)(w1hi + fo);
            short8 bl = *(const short8*)(w1lo + fo);
#pragma unroll
            for (int bd = 0; bd < 2; bd++) {
                acc2[bd][tn] = __builtin_amdgcn_mfma_f32_16x16x32_bf16(a[bd], bh, acc2[bd][tn], 0, 0, 0);
                acc2[bd][tn] = __builtin_amdgcn_mfma_f32_16x16x32_bf16(a[bd], bl, acc2[bd][tn], 0, 0, 0);
            }
        }
    }
    float invs[2][4];
#pragma unroll
    for (int bd = 0; bd < 2; bd++)
#pragma unroll
        for (int r = 0; r < 4; r++) {
            int grow = m0 + bd * 16 + lq + r; if (grow >= M) grow = M - 1;
            invs[bd][r] = inv_s[grow];
        }
#pragma unroll
    for (int bd = 0; bd < 2; bd++)
#pragma unroll
        for (int tn = 0; tn < 8; tn++)
#pragma unroll
            for (int r = 0; r < 4; r++)
                t1[w][bd * 16 + lq + r][tn * 16 + lr] =
                    f2bf(fmaxf(acc2[bd][tn][r] + b1v[tn], 0.f) * invs[bd][r]);
#pragma unroll
    for (int q = 0; q < 8; q++) {
        int s = q * 64 + L;
        int row = s >> 4, c0 = (s & 15) * 8;
        int grow = m0 + row;
        if (grow < M)
            *(short8*)(x16 + (size_t)grow * 128 + c0) = *(const short8*)&t1[w][row][c0];
    }
}

// ---------- agg step 0: 1 wave/node, 16/8/1 gather batches, writes h16 -------
__global__ __launch_bounds__(256) void k_agg_ln(
    const unsigned short* __restrict__ x16, const int* __restrict__ row_start,
    const int* __restrict__ edge_src, const float* __restrict__ inv_r,
    const float* __restrict__ ln_scale, const float* __restrict__ ln_offset,
    unsigned short* __restrict__ h16)
{
    int node = __builtin_amdgcn_readfirstlane(blockIdx.x * 4 + (threadIdx.x >> 6));
    int L = threadIdx.x & 63;
    const unsigned int* x32 = (const unsigned int*)x16;
    const unsigned int* h32 = (const unsigned int*)h16;

    unsigned int su = x32[(size_t)node * 64 + L];          // self loop
    float2 acc;
    acc.x = __uint_as_float(su << 16);
    acc.y = __uint_as_float(su & 0xffff0000u);

    int beg = row_start[node], end = row_start[node + 1];
    int j = beg;
    for (; j + 16 <= end; j += 16) {
        unsigned int u[16];
#pragma unroll
        for (int q = 0; q < 16; q++) u[q] = x32[(size_t)edge_src[j + q] * 64 + L];
#pragma unroll
        for (int q = 0; q < 16; q++) {
            acc.x += __uint_as_float(u[q] << 16);
            acc.y += __uint_as_float(u[q] & 0xffff0000u);
        }
    }
    for (; j + 8 <= end; j += 8) {
        unsigned int u[8];
#pragma unroll
        for (int q = 0; q < 8; q++) u[q] = x32[(size_t)edge_src[j + q] * 64 + L];
#pragma unroll
        for (int q = 0; q < 8; q++) {
            acc.x += __uint_as_float(u[q] << 16);
            acc.y += __uint_as_float(u[q] & 0xffff0000u);
        }
    }
    for (; j < end; j++) {
        unsigned int u0 = x32[(size_t)edge_src[j] * 64 + L];
        acc.x += __uint_as_float(u0 << 16);
        acc.y += __uint_as_float(u0 & 0xffff0000u);
    }

    float ir = inv_r[node];
    unsigned int hu = h32[(size_t)node * 64 + L];
    float y0 = acc.x * ir + __uint_as_float(hu << 16);
    float y1 = acc.y * ir + __uint_as_float(hu & 0xffff0000u);

    float s1 = y0 + y1, s2 = y0 * y0 + y1 * y1;
#pragma unroll
    for (int off = 32; off > 0; off >>= 1) {
        s1 += __shfl_xor(s1, off, 64);
        s2 += __shfl_xor(s2, off, 64);
    }
    float mu = s1 * (1.f / 128.f);
    float var = fmaxf(s2 * (1.f / 128.f) - mu * mu, 0.f);
    float rstd = rsqrtf(var + 1e-5f);
    float2 sc = *(const float2*)&ln_scale[L * 2];
    float2 of = *(const float2*)&ln_offset[L * 2];
    float ox = (y0 - mu) * rstd * sc.x + of.x;
    float oy = (y1 - mu) * rstd * sc.y + of.y;
    ((unsigned int*)h16)[(size_t)node * 64 + L] =
        (unsigned int)f2bf(ox) | ((unsigned int)f2bf(oy) << 16);
}

// ---------- agg step 1 + pooling: LN outputs block-summed, no h16 write ------
// 4 nodes/block all in one graph (4 | 1000). poolpart[bid][128] fp32.
__global__ __launch_bounds__(256) void k_agg_pool(
    const unsigned short* __restrict__ x16, const int* __restrict__ row_start,
    const int* __restrict__ edge_src, const float* __restrict__ inv_r,
    const float* __restrict__ ln_scale, const float* __restrict__ ln_offset,
    const unsigned short* __restrict__ h16, float* __restrict__ poolpart)
{
    __shared__ float2 part[4][64];
    int w = threadIdx.x >> 6, L = threadIdx.x & 63;
    int node = __builtin_amdgcn_readfirstlane(blockIdx.x * 4 + w);
    const unsigned int* x32 = (const unsigned int*)x16;
    const unsigned int* h32 = (const unsigned int*)h16;

    unsigned int su = x32[(size_t)node * 64 + L];          // self loop
    float2 acc;
    acc.x = __uint_as_float(su << 16);
    acc.y = __uint_as_float(su & 0xffff0000u);

    int beg = row_start[node], end = row_start[node + 1];
    int j = beg;
    for (; j + 16 <= end; j += 16) {
        unsigned int u[16];
#pragma unroll
        for (int q = 0; q < 16; q++) u[q] = x32[(size_t)edge_src[j + q] * 64 + L];
#pragma unroll
        for (int q = 0; q < 16; q++) {
            acc.x += __uint_as_float(u[q] << 16);
            acc.y += __uint_as_float(u[q] & 0xffff0000u);
        }
    }
    for (; j + 8 <= end; j += 8) {
        unsigned int u[8];
#pragma unroll
        for (int q = 0; q < 8; q++) u[q] = x32[(size_t)edge_src[j + q] * 64 + L];
#pragma unroll
        for (int q = 0; q < 8; q++) {
            acc.x += __uint_as_float(u[q] << 16);
            acc.y += __uint_as_float(u[q] & 0xffff0000u);
        }
    }
    for (; j < end; j++) {
        unsigned int u0 = x32[(size_t)edge_src[j] * 64 + L];
        acc.x += __uint_as_float(u0 << 16);
        acc.y += __uint_as_float(u0 & 0xffff0000u);
    }

    float ir = inv_r[node];
    unsigned int hu = h32[(size_t)node * 64 + L];
    float y0 = acc.x * ir + __uint_as_float(hu << 16);
    float y1 = acc.y * ir + __uint_as_float(hu & 0xffff0000u);

    float s1 = y0 + y1, s2 = y0 * y0 + y1 * y1;
#pragma unroll
    for (int off = 32; off > 0; off >>= 1) {
        s1 += __shfl_xor(s1, off, 64);
        s2 += __shfl_xor(s2, off, 64);
    }
    float mu = s1 * (1.f / 128.f);
    float var = fmaxf(s2 * (1.f / 128.f) - mu * mu, 0.f);
    float rstd = rsqrtf(var + 1e-5f);
    float2 sc = *(const float2*)&ln_scale[L * 2];
    float2 of = *(const float2*)&ln_offset[L * 2];
    float2 o;
    o.x = (y0 - mu) * rstd * sc.x + of.x;
    o.y = (y1 - mu) * rstd * sc.y + of.y;
    part[w][L] = o;
    __syncthreads();
    if (w == 0) {
        float2 p0 = part[0][L], p1 = part[1][L], p2 = part[2][L], p3 = part[3][L];
        float2 s;
        s.x = (p0.x + p1.x) + (p2.x + p3.x);
        s.y = (p0.y + p1.y) + (p2.y + p3.y);
        *(float2*)&poolpart[(size_t)blockIdx.x * 128 + L * 2] = s;
    }
}

// ---------- pool reduce level 1: 25000 partial rows -> 1000 ----------
__global__ __launch_bounds__(128) void k_pool2(const float* __restrict__ poolpart,
                                               float* __restrict__ poolpart2) {
    int b = blockIdx.x, col = threadIdx.x;    // b in [0,1000): graph g=b/10, chunk c=b%10
    const float* pg = poolpart + ((size_t)b * 25) * 128;
    float s = 0.f;
#pragma unroll
    for (int k = 0; k < 25; k++) s += pg[k * 128 + col];
    poolpart2[(size_t)b * 128 + col] = s;
}

// ---------- pool reduce level 2 + decode ----------
__global__ __launch_bounds__(128) void k_pool3(const float* __restrict__ poolpart2,
                                               const float* __restrict__ dec_w,
                                               const float* __restrict__ dec_b,
                                               float* __restrict__ out) {
    int g = blockIdx.x, col = threadIdx.x;    // 128 threads
    const float* pg = poolpart2 + (size_t)g * 10 * 128;
    float s = 0.f;
#pragma unroll
    for (int c = 0; c < 10; c++) s += pg[c * 128 + col];
    s = s * (1.f / (float)NPG) * dec_w[col];
    __shared__ float ws[2];
#pragma unroll
    for (int off = 32; off > 0; off >>= 1) s += __shfl_down(s, off, 64);
    if ((col & 63) == 0) ws[col >> 6] = s;
    __syncthreads();
    if (col == 0) out[g] = ws[0] + ws[1] + dec_b[0];
}

extern "C" void kernel_launch(void* const* d_in, const int* in_sizes, int n_in,
                              void* d_out, int out_size, void* d_ws, size_t ws_size,
                              hipStream_t stream) {
    (void)in_sizes; (void)n_in; (void)out_size; (void)ws_size;
    const float* nodes     = (const float*)d_in[0];
    const int*   senders   = (const int*)d_in[1];
    const int*   receivers = (const int*)d_in[2];
    const float* embed_w   = (const float*)d_in[4];
    const float* embed_b   = (const float*)d_in[5];
    const float* mlp_w     = (const float*)d_in[6];
    const float* mlp_b     = (const float*)d_in[7];
    const float* ln_scale  = (const float*)d_in[8];
    const float* ln_offset = (const float*)d_in[9];
    const float* dec_w     = (const float*)d_in[10];
    const float* dec_b     = (const float*)d_in[11];
    float* out = (float*)d_out;

    const int N = N_NODES;
    const int WF_TOTAL = 8192 + 4 * 16384;          // frag elements (shorts)
    const size_t PART_TOTAL = (size_t)NPART * NSLICE * PSIZE;  // 6.4M entries

    char* p = (char*)d_ws;
    auto alloc = [&](size_t bytes) -> void* {
        void* r = (void*)p;
        p += (bytes + 255) & ~(size_t)255;
        return r;
    };
    unsigned short* h16      = (unsigned short*)alloc((size_t)N * 128 * 2);
    unsigned short* x16      = (unsigned short*)alloc((size_t)N * 128 * 2);
    int*            edge_src = (int*)alloc((size_t)N_EDGES * 4);
    unsigned short* ps16     = (unsigned short*)alloc(PART_TOTAL * 2);
    unsigned short* pr16     = (unsigned short*)alloc(PART_TOTAL * 2);
    int*            deg_r    = (int*)alloc((size_t)N * 4);
    float*          inv_s    = (float*)alloc((size_t)N * 4);
    float*          inv_r    = (float*)alloc((size_t)N * 4);
    int*            row_start= (int*)alloc((size_t)(N + 1) * 4);
    int*            blocksums= (int*)alloc((size_t)SCAN_NB * 4);
    unsigned short* wfhi     = (unsigned short*)alloc((size_t)WF_TOTAL * 2);
    unsigned short* wflo     = (unsigned short*)alloc((size_t)WF_TOTAL * 2);
    float*          poolpart = (float*)alloc((size_t)(N / 4) * 128 * 4);
    float*          poolpart2= (float*)alloc((size_t)1000 * 128 * 4);

    k_wprep<<<(WF_TOTAL + 255) / 256, 256, 0, stream>>>(embed_w, mlp_w, wfhi, wflo);

    // graph prep — no global atomics
    k_hist2<<<NPART * NSLICE, 1024, 0, stream>>>(senders, receivers, ps16, pr16);
    k_scan_slices<<<(N + 255) / 256, 256, 0, stream>>>(ps16, pr16, deg_r, inv_s, inv_r);
    k_scan_block<<<SCAN_NB, 256, 0, stream>>>(deg_r, blocksums, N);
    k_scan_apply<<<SCAN_NB, 256, 0, stream>>>(deg_r, blocksums, row_start, N);
    k_fill2<<<NPART * NSLICE, 1024, 0, stream>>>(senders, receivers, pr16, row_start, edge_src);

    int mblocks = (N + 127) / 128;
    const unsigned short* wehi = wfhi, *welo = wflo;
    const unsigned short* w0hi[2] = { wfhi + 8192,             wfhi + 8192 + 2 * 16384 };
    const unsigned short* w0lo[2] = { wflo + 8192,             wflo + 8192 + 2 * 16384 };
    const unsigned short* w1hi[2] = { wfhi + 8192 + 16384,     wfhi + 8192 + 3 * 16384 };
    const unsigned short* w1lo[2] = { wflo + 8192 + 16384,     wflo + 8192 + 3 * 16384 };

    // step 0: fused embed + MLP, then agg+LN into h16
    k_embed_mlp<<<mblocks, 256, 0, stream>>>(nodes, wehi, welo, embed_b,
                                             w0hi[0], w0lo[0], w1hi[0], w1lo[0],
                                             mlp_b, mlp_b + 128, inv_s, h16, x16, N);
    k_agg_ln<<<N / 4, 256, 0, stream>>>(x16, row_start, edge_src, inv_r,
                                        ln_scale, ln_offset, h16);
    // step 1: MLP, then agg+LN fused with pooling (no h16 write)
    k_mlp<<<mblocks, 256, 0, stream>>>(h16, w0hi[1], w0lo[1], w1hi[1], w1lo[1],
                                       mlp_b + 256, mlp_b + 384, inv_s, x16, N);
    k_agg_pool<<<N / 4, 256, 0, stream>>>(x16, row_start, edge_src, inv_r,
                                          ln_scale + 128, ln_offset + 128, h16, poolpart);

    k_pool2<<<1000, 128, 0, stream>>>(poolpart, poolpart2);
    k_pool3<<<N_GRAPH, 128, 0, stream>>>(poolpart2, dec_w, dec_b, out);
}